// Round 16
// baseline (255.850 us; speedup 1.0000x reference)
//
#include <hip/hip_runtime.h>

#define NF_IN 256
#define NF 128
#define NEG_SLOPE 0.2f
#define BUCKET 64   // padded CSR capacity/node; deg~Poisson(16), P(deg>64)~1e-28

// ---- stage A: column sums of attention matrix a[256][256] -> av[256] ----
__global__ __launch_bounds__(256) void stage_colsum(const float* __restrict__ a,
                                                    float* __restrict__ av) {
    float s = 0.f;
    const int r0 = blockIdx.x * 32;
    const int c = threadIdx.x;
    for (int i = 0; i < 32; ++i) s += a[(size_t)(r0 + i) * (2 * NF) + c];
    atomicAdd(&av[c], s);
}

// ---- stage B: projection h = x @ W, fp32; tile 32x128 (2x grid of R15) ----
// 256 threads = 32 col-groups x 8 row-groups; thread owns 4 rows x (2+2 split) cols.
// Split cols (cc*2, 64+cc*2): W b64 reads 2-way bank-aliased (free, m136).
// x b128 reads: rr*4 rows -> 8 distinct bank quads, broadcast over cc (free).
// Epilogue: scs[r] = h[r]·av[:128]; scd[r] = h[r]·av[128:] (32-lane reduce).
#define MT 32
#define KT 32
__global__ __launch_bounds__(256) void stage_proj(const float* __restrict__ x,
                                                  const float* __restrict__ W,
                                                  const float* __restrict__ av,
                                                  float* __restrict__ h,
                                                  float* __restrict__ scs,
                                                  float* __restrict__ scd, int n) {
    __shared__ float shx[KT][MT + 4];   // 4.6 KB, transposed x tile
    __shared__ float shw[KT][NF];       // 16 KB

    const int tid = threadIdx.x;
    const int cc = tid & 31;    // col group: cols cc*2..+1 and 64+cc*2..+1
    const int rr = tid >> 5;    // row group: rows rr*4..+3
    const int rbase = blockIdx.x * MT;

    float avA[4], avB[4];
    avA[0] = av[cc * 2];           avA[1] = av[cc * 2 + 1];
    avA[2] = av[64 + cc * 2];      avA[3] = av[64 + cc * 2 + 1];
    avB[0] = av[NF + cc * 2];      avB[1] = av[NF + cc * 2 + 1];
    avB[2] = av[NF + 64 + cc * 2]; avB[3] = av[NF + 64 + cc * 2 + 1];

    float acc[4][4];
    #pragma unroll
    for (int r = 0; r < 4; ++r)
        #pragma unroll
        for (int c = 0; c < 4; ++c) acc[r][c] = 0.f;

    const int ldr = tid & 31;           // x-stage row within tile
    const int ldk = (tid >> 5) * 4;     // x-stage k offset: 0,4,...,28
    int gr = rbase + ldr;
    if (gr >= n) gr = n - 1;
    const float* xrow = x + (size_t)gr * NF_IN;

    for (int k0 = 0; k0 < NF_IN; k0 += KT) {
        {
            const float4 u = *(const float4*)(xrow + k0 + ldk);
            shx[ldk + 0][ldr] = u.x;
            shx[ldk + 1][ldr] = u.y;
            shx[ldk + 2][ldr] = u.z;
            shx[ldk + 3][ldr] = u.w;
        }
        {
            const float4* gw = (const float4*)(W + (size_t)k0 * NF);
            float4* lw4 = (float4*)(&shw[0][0]);
            #pragma unroll
            for (int i = 0; i < 4; ++i) lw4[tid + i * 256] = gw[tid + i * 256];
        }
        __syncthreads();

        #pragma unroll 8
        for (int k = 0; k < KT; ++k) {
            const float4 xv = *(float4*)(&shx[k][rr * 4]);
            const float2 wa = *(float2*)(&shw[k][cc * 2]);
            const float2 wb = *(float2*)(&shw[k][64 + cc * 2]);
            const float xf[4] = {xv.x, xv.y, xv.z, xv.w};
            const float wf[4] = {wa.x, wa.y, wb.x, wb.y};
            #pragma unroll
            for (int r = 0; r < 4; ++r)
                #pragma unroll
                for (int c = 0; c < 4; ++c) acc[r][c] += xf[r] * wf[c];
        }
        __syncthreads();
    }

    #pragma unroll
    for (int r = 0; r < 4; ++r) {
        const int row = rbase + rr * 4 + r;
        float ps = 0.f, pd = 0.f;
        #pragma unroll
        for (int c = 0; c < 4; ++c) {
            ps += acc[r][c] * avA[c];
            pd += acc[r][c] * avB[c];
        }
        #pragma unroll
        for (int m = 1; m <= 16; m <<= 1) {
            ps += __shfl_xor(ps, m, 64);
            pd += __shfl_xor(pd, m, 64);
        }
        if (row < n) {
            float* hp = h + (size_t)row * NF;
            *(float2*)(hp + cc * 2) = make_float2(acc[r][0], acc[r][1]);
            *(float2*)(hp + 64 + cc * 2) = make_float2(acc[r][2], acc[r][3]);
            if (cc == 0) { scs[row] = ps; scd[row] = pd; }
        }
    }
}

// ---- stage C: direct scatter into padded CSR (1 atomic + 1 store / edge) ----
__global__ __launch_bounds__(256) void stage_fill(const int4* __restrict__ sv,
                                                  const int4* __restrict__ dv,
                                                  int* __restrict__ deg,
                                                  int* __restrict__ nbr, int m4) {
    const int i = blockIdx.x * blockDim.x + threadIdx.x;
    if (i >= m4) return;
    const int4 s = sv[i];
    const int4 d = dv[i];
    int k;
    k = atomicAdd(deg + s.x, 1); if (k < BUCKET) nbr[(s.x << 6) + k] = d.x;
    k = atomicAdd(deg + s.y, 1); if (k < BUCKET) nbr[(s.y << 6) + k] = d.y;
    k = atomicAdd(deg + s.z, 1); if (k < BUCKET) nbr[(s.z << 6) + k] = d.z;
    k = atomicAdd(deg + s.w, 1); if (k < BUCKET) nbr[(s.w << 6) + k] = d.w;
}

// ---- stage D: aggregation; 1 wave/node, 8 subgroups x 8 lanes ----
// lane = sub*8+qq owns features qq*16..+15; lin = scs[node]+scd[dst];
// only conv needs an 8-lane reduce.
__global__ __launch_bounds__(256) void stage_agg(const float* __restrict__ h,
                                                 const int* __restrict__ nbr,
                                                 const int* __restrict__ deg,
                                                 const float* __restrict__ scs,
                                                 const float* __restrict__ scd,
                                                 float* __restrict__ out, int n) {
    const int node = (blockIdx.x * blockDim.x + threadIdx.x) >> 6;
    if (node >= n) return;
    const int lane = threadIdx.x & 63;
    const int qq = lane & 7;
    const int sub = lane >> 3;

    const float4* hself = (const float4*)(h + (size_t)node * NF);
    const float4 p0 = hself[qq * 4 + 0];
    const float4 p1 = hself[qq * 4 + 1];
    const float4 p2 = hself[qq * 4 + 2];
    const float4 p3 = hself[qq * 4 + 3];

    const float lbase = scs[node];
    const int org = node << 6;   // BUCKET = 64
    int dg = deg[node];
    if (dg > BUCKET) dg = BUCKET;

    float4 t0 = make_float4(0.f, 0.f, 0.f, 0.f);
    float4 t1 = make_float4(0.f, 0.f, 0.f, 0.f);
    float4 t2 = make_float4(0.f, 0.f, 0.f, 0.f);
    float4 t3 = make_float4(0.f, 0.f, 0.f, 0.f);
    float zsum = 0.f;

    if (dg > 0) {
        int cu = nbr[org + ((sub < dg) ? sub : 0)];
        float lcu = scd[cu];
        for (int j = 0; j < dg; j += 8) {
            int nx = 0;
            float lnx = 0.f;
            if (j + 8 < dg) {
                const int jj = j + 8 + sub;
                nx = nbr[org + ((jj < dg) ? jj : 0)];
                lnx = scd[nx];
            }
            const float4* hn = (const float4*)(h + (size_t)cu * NF);
            const float4 q0 = hn[qq * 4 + 0];
            const float4 q1 = hn[qq * 4 + 1];
            const float4 q2 = hn[qq * 4 + 2];
            const float4 q3 = hn[qq * 4 + 3];

            float cv = p0.x * q0.x + p0.y * q0.y + p0.z * q0.z + p0.w * q0.w
                     + p1.x * q1.x + p1.y * q1.y + p1.z * q1.z + p1.w * q1.w
                     + p2.x * q2.x + p2.y * q2.y + p2.z * q2.z + p2.w * q2.w
                     + p3.x * q3.x + p3.y * q3.y + p3.z * q3.z + p3.w * q3.w;
            #pragma unroll
            for (int m = 4; m >= 1; m >>= 1) cv += __shfl_xor(cv, m, 64);

            const float gate = 1.0f / (1.0f + __expf(-cv));
            const float zz = (lbase + lcu) * gate;
            const float zr = (zz >= 0.f) ? zz : NEG_SLOPE * zz;
            float wt = __expf(-zr);
            if (j + sub >= dg) wt = 0.f;

            t0.x += wt * q0.x; t0.y += wt * q0.y; t0.z += wt * q0.z; t0.w += wt * q0.w;
            t1.x += wt * q1.x; t1.y += wt * q1.y; t1.z += wt * q1.z; t1.w += wt * q1.w;
            t2.x += wt * q2.x; t2.y += wt * q2.y; t2.z += wt * q2.z; t2.w += wt * q2.w;
            t3.x += wt * q3.x; t3.y += wt * q3.y; t3.z += wt * q3.z; t3.w += wt * q3.w;
            zsum += wt;

            cu = nx;
            lcu = lnx;
        }
    }

    #pragma unroll
    for (int m = 8; m <= 32; m <<= 1) {
        t0.x += __shfl_xor(t0.x, m, 64); t0.y += __shfl_xor(t0.y, m, 64);
        t0.z += __shfl_xor(t0.z, m, 64); t0.w += __shfl_xor(t0.w, m, 64);
        t1.x += __shfl_xor(t1.x, m, 64); t1.y += __shfl_xor(t1.y, m, 64);
        t1.z += __shfl_xor(t1.z, m, 64); t1.w += __shfl_xor(t1.w, m, 64);
        t2.x += __shfl_xor(t2.x, m, 64); t2.y += __shfl_xor(t2.y, m, 64);
        t2.z += __shfl_xor(t2.z, m, 64); t2.w += __shfl_xor(t2.w, m, 64);
        t3.x += __shfl_xor(t3.x, m, 64); t3.y += __shfl_xor(t3.y, m, 64);
        t3.z += __shfl_xor(t3.z, m, 64); t3.w += __shfl_xor(t3.w, m, 64);
        zsum += __shfl_xor(zsum, m, 64);
    }

    const float norm = 1.0f / (zsum + 1e-8f);
    const float4 m01 = (sub & 2) ? t1 : t0;
    const float4 m23 = (sub & 2) ? t3 : t2;
    const float4 sel = (sub & 4) ? m23 : m01;
    float y0 = ((sub & 1) ? sel.z : sel.x) * norm;
    float y1 = ((sub & 1) ? sel.w : sel.y) * norm;
    y0 = (y0 > 0.f) ? y0 : (__expf(y0) - 1.f);
    y1 = (y1 > 0.f) ? y1 : (__expf(y1) - 1.f);
    *(float2*)(out + (size_t)node * NF + qq * 16 + sub * 2) = make_float2(y0, y1);
}

extern "C" void kernel_launch(void* const* d_in, const int* in_sizes, int n_in,
                              void* d_out, int out_size, void* d_ws, size_t ws_size,
                              hipStream_t stream) {
    const float* x = (const float*)d_in[0];
    const int* ei = (const int*)d_in[1];
    const float* W = (const float*)d_in[2];
    const float* a = (const float*)d_in[3];
    float* out = (float*)d_out;

    const int n = in_sizes[0] / NF_IN;
    const int E = in_sizes[1] / 2;
    const int m4 = E / 4;
    const int* srcp = ei;
    const int* dstp = ei + E;

    char* w = (char*)d_ws;
    float* h = (float*)w;     w += (size_t)n * NF * 4;       // 25.6 MB
    float* scs = (float*)w;   w += (size_t)n * 4;
    float* scd = (float*)w;   w += (size_t)n * 4;
    float* av = (float*)w;    w += 256 * 4;                  // zero-region start
    int* deg = (int*)w;       w += (size_t)n * 4;            // contiguous with av
    int* nbr = (int*)w;       w += (size_t)n * BUCKET * 4;   // 12.8 MB

    hipMemsetAsync(av, 0, (256 + (size_t)n) * sizeof(int), stream);

    stage_colsum<<<8, 256, 0, stream>>>(a, av);
    stage_proj<<<(n + MT - 1) / MT, 256, 0, stream>>>(x, W, av, h, scs, scd, n);
    stage_fill<<<(m4 + 255) / 256, 256, 0, stream>>>((const int4*)srcp, (const int4*)dstp,
                                                     deg, nbr, m4);
    stage_agg<<<((size_t)n * 64 + 255) / 256, 256, 0, stream>>>(h, nbr, deg, scs, scd,
                                                                out, n);
}